// Round 8
// baseline (2254.467 us; speedup 1.0000x reference)
//
#include <hip/hip_runtime.h>
#include <stdint.h>

#define NSITES 256
#define NHID   64
#define BATCH  8192

typedef float v4f __attribute__((ext_vector_type(4)));

// ---------------- threefry2x32 (exact JAX semantics) ----------------
__device__ __forceinline__ uint32_t rotl32(uint32_t v, int d) {
  return (v << d) | (v >> (32 - d));
}

__device__ __forceinline__ void tf2x32(uint32_t k0, uint32_t k1,
                                       uint32_t x0, uint32_t x1,
                                       uint32_t& o0, uint32_t& o1) {
  uint32_t ks2 = k0 ^ k1 ^ 0x1BD11BDAu;
  x0 += k0; x1 += k1;
#define TFR4(a,b,c,d) \
  x0 += x1; x1 = rotl32(x1,a); x1 ^= x0; \
  x0 += x1; x1 = rotl32(x1,b); x1 ^= x0; \
  x0 += x1; x1 = rotl32(x1,c); x1 ^= x0; \
  x0 += x1; x1 = rotl32(x1,d); x1 ^= x0;
  TFR4(13,15,26,6)   x0 += k1;  x1 += ks2 + 1u;
  TFR4(17,29,16,24)  x0 += ks2; x1 += k0  + 2u;
  TFR4(13,15,26,6)   x0 += k0;  x1 += k1  + 3u;
  TFR4(17,29,16,24)  x0 += k1;  x1 += ks2 + 4u;
  TFR4(13,15,26,6)   x0 += ks2; x1 += k0  + 5u;
#undef TFR4
  o0 = x0; o1 = x1;
}

__device__ __forceinline__ float gumb_from_bits(uint32_t bits) {
  float f = __uint_as_float((bits >> 9) | 0x3f800000u) - 1.0f;
  float u = (f == 0.0f) ? 1.17549435e-38f : f;
  return -logf(-logf(u));
}

__device__ __forceinline__ uint32_t rbits32(uint32_t k0, uint32_t k1, uint32_t e) {
  uint32_t a, b;
  tf2x32(k0, k1, 0u, e, a, b);
  return a ^ b;
}

// ---------------- gumbel precompute kernel ----------------
__global__ void gumbel_precompute(float2* __restrict__ g) {
  int idx = blockIdx.x * blockDim.x + threadIdx.x;
  if (idx >= NSITES * BATCH) return;
  int t = idx >> 13;
  int b = idx & (BATCH - 1);
  uint32_t kt0, kt1;
  tf2x32(0u, 1234u, 0u, (uint32_t)t, kt0, kt1);
  uint32_t r0 = rbits32(kt0, kt1, (uint32_t)(2 * b));
  uint32_t r1 = rbits32(kt0, kt1, (uint32_t)(2 * b + 1));
  g[idx] = make_float2(gumb_from_bits(r0), gumb_from_bits(r1));
}

// ---------------- Wh transpose: WhT[(gate*64+l)*64 + j] = Wh[j*192+gate*64+l]
__global__ void transpose_wh(const float* __restrict__ Wh, float* __restrict__ WhT) {
  int idx = blockIdx.x * 256 + threadIdx.x;   // 0..12287
  if (idx >= 3 * 64 * 64) return;
  int gate = idx >> 12;
  int rem  = idx & 4095;
  int l    = rem >> 6;
  int j    = rem & 63;
  WhT[idx] = Wh[j * 192 + gate * 64 + l];
}

// XLA's logistic_expander form: 0.5 + 0.5*tanh(0.5*x)
__device__ __forceinline__ float sigmoid_xla(float x) {
  return 0.5f + 0.5f * tanhf(0.5f * x);
}

// opaque load: cannot be rematerialized by the register allocator
#define ASM_LD4(dst, ptr) \
  asm volatile("global_load_dwordx4 %0, %1, off" : "=v"(dst) : "v"(ptr))

// ===== shared body: LDSB=false -> readlane h-broadcast, true -> LDS row ====
template <bool LDSB>
__device__ __forceinline__ void rnn_body(
    const float* __restrict__ Wi, const float* __restrict__ WhT,
    const float* __restrict__ bb, const float* __restrict__ Wd,
    const float* __restrict__ bd, const float2* __restrict__ g,
    float* __restrict__ out_s, float* __restrict__ out_lp,
    int lane, int b, float* hlds) {
  // ---- 48 opaque dwordx4 loads: lane's 192 weights, contiguous in WhT ----
  v4f wz4[16], wr4[16], wh4[16];
  const float* pz = WhT + (size_t)lane * 64;
  const float* pr = WhT + (size_t)(64 + lane) * 64;
  const float* ph = WhT + (size_t)(128 + lane) * 64;
#pragma unroll
  for (int j4 = 0; j4 < 16; ++j4) {
    ASM_LD4(wz4[j4], pz + 4 * j4);
    ASM_LD4(wr4[j4], pr + 4 * j4);
    ASM_LD4(wh4[j4], ph + 4 * j4);
  }
  asm volatile("s_waitcnt vmcnt(0)" ::: "memory");
  __builtin_amdgcn_sched_barrier(0);

  const float b1z = bb[192 + lane];
  const float b1r = bb[192 + 64 + lane];
  const float b1h = bb[192 + 128 + lane];
  const float m0z = bb[lane], m0r = bb[64 + lane], m0h = bb[128 + lane];
  const float m1z = Wi[lane] + m0z, m1r = Wi[64 + lane] + m0r, m1h = Wi[128 + lane] + m0h;
  const float m2z = Wi[192 + lane] + m0z, m2r = Wi[192 + 64 + lane] + m0r,
              m2h = Wi[192 + 128 + lane] + m0h;
  const float wd0 = Wd[lane * 2 + 0], wd1 = Wd[lane * 2 + 1];
  const float bd0 = bd[0], bd1 = bd[1];

  float h = 0.0f, lpsum = 0.0f;
  float xz = m0z, xr = m0r, xh = m0h;   // t=0: zero one-hot input
  if (LDSB) hlds[lane] = 0.0f;

  for (int t = 0; t < NSITES; ++t) {
    const float2 gc = g[t * BATCH + b];
    const float g0 = gc.x, g1 = gc.y;

    // mh = h @ Wh (identical fmaf chain, j ascending)
    float az = 0.0f, ar = 0.0f, ah = 0.0f;
    if (LDSB) {
#pragma unroll
      for (int j4 = 0; j4 < 16; ++j4) {
        // wave-uniform address -> broadcast ds_read_b128, same bits as readlane
        const float4 hv = *reinterpret_cast<const float4*>(&hlds[4 * j4]);
        az = fmaf(hv.x, wz4[j4][0], az); ar = fmaf(hv.x, wr4[j4][0], ar); ah = fmaf(hv.x, wh4[j4][0], ah);
        az = fmaf(hv.y, wz4[j4][1], az); ar = fmaf(hv.y, wr4[j4][1], ar); ah = fmaf(hv.y, wh4[j4][1], ah);
        az = fmaf(hv.z, wz4[j4][2], az); ar = fmaf(hv.z, wr4[j4][2], ar); ah = fmaf(hv.z, wh4[j4][2], ah);
        az = fmaf(hv.w, wz4[j4][3], az); ar = fmaf(hv.w, wr4[j4][3], ar); ah = fmaf(hv.w, wh4[j4][3], ah);
      }
    } else {
#pragma unroll
      for (int j = 0; j < NHID; ++j) {
        const float hj = __int_as_float(__builtin_amdgcn_readlane(__float_as_int(h), j));
        az = fmaf(hj, wz4[j >> 2][j & 3], az);
        ar = fmaf(hj, wr4[j >> 2][j & 3], ar);
        ah = fmaf(hj, wh4[j >> 2][j & 3], ah);
      }
    }
    const float rz = az + b1z;
    const float rr = ar + b1r;
    const float rh = ah + b1h;

    const float zg = sigmoid_xla(xz + rz);
    const float rg = sigmoid_xla(xr + rr);
    const float hg = tanhf(xh + rg * rh);
    h = zg * h + (1.0f - zg) * hg;
    if (LDSB) hlds[lane] = h;   // publish for next step's broadcast

    float p0 = h * wd0, p1 = h * wd1;
#pragma unroll
    for (int off = 32; off > 0; off >>= 1) {
      p0 += __shfl_xor(p0, off, 64);
      p1 += __shfl_xor(p1, off, 64);
    }
    const float l0 = p0 + bd0, l1 = p1 + bd1;

    const float mmax = fmaxf(l0, l1);
    const float sh0 = l0 - mmax, sh1 = l1 - mmax;
    const float lse = logf(expf(sh0) + expf(sh1));

    const int s = ((l1 + g1) > (l0 + g0)) ? 1 : 0;

    lpsum += (s ? sh1 : sh0) - lse;
    if (lane == 0) out_s[(size_t)b * NSITES + t] = (float)s;
    xz = s ? m2z : m1z;
    xr = s ? m2r : m1r;
    xh = s ? m2h : m1h;
  }

  if (lane == 0) out_lp[b] = 0.5f * lpsum;
}

// vA: readlane broadcast (current math), 512-reg budget
__global__ __launch_bounds__(64) __attribute__((amdgpu_waves_per_eu(1, 1)))
void rnn_vA(const float* __restrict__ Wi, const float* __restrict__ WhT,
            const float* __restrict__ bb, const float* __restrict__ Wd,
            const float* __restrict__ bd, const float2* __restrict__ g,
            float* __restrict__ out_s, float* __restrict__ out_lp) {
  rnn_body<false>(Wi, WhT, bb, Wd, bd, g, out_s, out_lp,
                  threadIdx.x, blockIdx.x, nullptr);
}

// vB: LDS h-broadcast (1 ds_write + 16 uniform ds_read_b128 per step)
__global__ __launch_bounds__(64) __attribute__((amdgpu_waves_per_eu(1, 1)))
void rnn_vB(const float* __restrict__ Wi, const float* __restrict__ WhT,
            const float* __restrict__ bb, const float* __restrict__ Wd,
            const float* __restrict__ bd, const float2* __restrict__ g,
            float* __restrict__ out_s, float* __restrict__ out_lp) {
  __shared__ float hlds[NHID];
  rnn_body<true>(Wi, WhT, bb, Wd, bd, g, out_s, out_lp,
                 threadIdx.x, (int)blockIdx.x + BATCH / 2, hlds);
}

// ---------------- fallback (ws too small): plain bit-exact path ----------
__global__ __launch_bounds__(64)
void rnn_plain(const float* __restrict__ Wi, const float* __restrict__ Wh,
               const float* __restrict__ bb, const float* __restrict__ Wd,
               const float* __restrict__ bd,
               float* __restrict__ out_s, float* __restrict__ out_lp) {
  const int lane = threadIdx.x;
  const int b = blockIdx.x;

  float wz[NHID], wr[NHID], wh[NHID];
#pragma unroll
  for (int j = 0; j < NHID; ++j) {
    wz[j] = Wh[j * 192 + lane];
    wr[j] = Wh[j * 192 + 64 + lane];
    wh[j] = Wh[j * 192 + 128 + lane];
  }
  const float b1z = bb[192 + lane];
  const float b1r = bb[192 + 64 + lane];
  const float b1h = bb[192 + 128 + lane];
  const float m0z = bb[lane], m0r = bb[64 + lane], m0h = bb[128 + lane];
  const float m1z = Wi[lane] + m0z, m1r = Wi[64 + lane] + m0r, m1h = Wi[128 + lane] + m0h;
  const float m2z = Wi[192 + lane] + m0z, m2r = Wi[192 + 64 + lane] + m0r,
              m2h = Wi[192 + 128 + lane] + m0h;
  const float wd0 = Wd[lane * 2 + 0], wd1 = Wd[lane * 2 + 1];
  const float bd0 = bd[0], bd1 = bd[1];

  float h = 0.0f, lpsum = 0.0f;
  float xz = m0z, xr = m0r, xh = m0h;

  for (int t = 0; t < NSITES; ++t) {
    uint32_t kt0, kt1;
    tf2x32(0u, 1234u, 0u, (uint32_t)t, kt0, kt1);
    const float g0 = gumb_from_bits(rbits32(kt0, kt1, (uint32_t)(2 * b)));
    const float g1 = gumb_from_bits(rbits32(kt0, kt1, (uint32_t)(2 * b + 1)));

    float az = 0.0f, ar = 0.0f, ah = 0.0f;
#pragma unroll
    for (int j = 0; j < NHID; ++j) {
      const float hj = __int_as_float(__builtin_amdgcn_readlane(__float_as_int(h), j));
      az = fmaf(hj, wz[j], az);
      ar = fmaf(hj, wr[j], ar);
      ah = fmaf(hj, wh[j], ah);
    }
    const float rz = az + b1z, rr = ar + b1r, rh = ah + b1h;
    const float zg = sigmoid_xla(xz + rz);
    const float rg = sigmoid_xla(xr + rr);
    const float hg = tanhf(xh + rg * rh);
    h = zg * h + (1.0f - zg) * hg;

    float p0 = h * wd0, p1 = h * wd1;
#pragma unroll
    for (int off = 32; off > 0; off >>= 1) {
      p0 += __shfl_xor(p0, off, 64);
      p1 += __shfl_xor(p1, off, 64);
    }
    const float l0 = p0 + bd0, l1 = p1 + bd1;
    const float mmax = fmaxf(l0, l1);
    const float sh0 = l0 - mmax, sh1 = l1 - mmax;
    const float lse = logf(expf(sh0) + expf(sh1));
    const int s = ((l1 + g1) > (l0 + g0)) ? 1 : 0;
    lpsum += (s ? sh1 : sh0) - lse;
    if (lane == 0) out_s[(size_t)b * NSITES + t] = (float)s;
    xz = s ? m2z : m1z;
    xr = s ? m2r : m1r;
    xh = s ? m2h : m1h;
  }

  if (lane == 0) out_lp[b] = 0.5f * lpsum;
}

extern "C" void kernel_launch(void* const* d_in, const int* in_sizes, int n_in,
                              void* d_out, int out_size, void* d_ws, size_t ws_size,
                              hipStream_t stream) {
  const float* Wi = (const float*)d_in[1];
  const float* Wh = (const float*)d_in[2];
  const float* bb = (const float*)d_in[3];
  const float* Wd = (const float*)d_in[4];
  const float* bd = (const float*)d_in[5];

  float* out    = (float*)d_out;
  float* out_s  = out;                           // [8192][256]
  float* out_lp = out + (size_t)BATCH * NSITES;  // [8192]

  const size_t gbytes  = (size_t)NSITES * BATCH * sizeof(float2);  // 16 MiB
  const size_t whbytes = (size_t)3 * 64 * 64 * sizeof(float);      // 48 KiB

  if (ws_size >= gbytes + whbytes) {
    float2* g   = (float2*)d_ws;
    float* WhT  = (float*)((char*)d_ws + gbytes);
    gumbel_precompute<<<(NSITES * BATCH) / 256, 256, 0, stream>>>(g);
    transpose_wh<<<(3 * 64 * 64 + 255) / 256, 256, 0, stream>>>(Wh, WhT);
    // within-probe A/B: vA on [0,4096), vB on [4096,8192)
    rnn_vA<<<BATCH / 2, 64, 0, stream>>>(Wi, WhT, bb, Wd, bd, g, out_s, out_lp);
    rnn_vB<<<BATCH / 2, 64, 0, stream>>>(Wi, WhT, bb, Wd, bd, g, out_s, out_lp);
  } else {
    rnn_plain<<<BATCH, 64, 0, stream>>>(Wi, Wh, bb, Wd, bd, out_s, out_lp);
  }
}

// Round 9
// 1330.423 us; speedup vs baseline: 1.6945x; 1.6945x over previous
//
#include <hip/hip_runtime.h>
#include <stdint.h>

#define NSITES 256
#define NHID   64
#define BATCH  8192

typedef float v4f __attribute__((ext_vector_type(4)));
typedef short v8s __attribute__((ext_vector_type(8)));

// ---------------- threefry2x32 (exact JAX semantics) ----------------
__device__ __forceinline__ uint32_t rotl32(uint32_t v, int d) {
  return (v << d) | (v >> (32 - d));
}

__device__ __forceinline__ void tf2x32(uint32_t k0, uint32_t k1,
                                       uint32_t x0, uint32_t x1,
                                       uint32_t& o0, uint32_t& o1) {
  uint32_t ks2 = k0 ^ k1 ^ 0x1BD11BDAu;
  x0 += k0; x1 += k1;
#define TFR4(a,b,c,d) \
  x0 += x1; x1 = rotl32(x1,a); x1 ^= x0; \
  x0 += x1; x1 = rotl32(x1,b); x1 ^= x0; \
  x0 += x1; x1 = rotl32(x1,c); x1 ^= x0; \
  x0 += x1; x1 = rotl32(x1,d); x1 ^= x0;
  TFR4(13,15,26,6)   x0 += k1;  x1 += ks2 + 1u;
  TFR4(17,29,16,24)  x0 += ks2; x1 += k0  + 2u;
  TFR4(13,15,26,6)   x0 += k0;  x1 += k1  + 3u;
  TFR4(17,29,16,24)  x0 += k1;  x1 += ks2 + 4u;
  TFR4(13,15,26,6)   x0 += ks2; x1 += k0  + 5u;
#undef TFR4
  o0 = x0; o1 = x1;
}

__device__ __forceinline__ float gumb_from_bits(uint32_t bits) {
  float f = __uint_as_float((bits >> 9) | 0x3f800000u) - 1.0f;
  float u = (f == 0.0f) ? 1.17549435e-38f : f;
  return -logf(-logf(u));
}

__device__ __forceinline__ uint32_t rbits32(uint32_t k0, uint32_t k1, uint32_t e) {
  uint32_t a, b;
  tf2x32(k0, k1, 0u, e, a, b);
  return a ^ b;
}

__global__ void gumbel_precompute(float2* __restrict__ g) {
  int idx = blockIdx.x * blockDim.x + threadIdx.x;
  if (idx >= NSITES * BATCH) return;
  int t = idx >> 13;
  int b = idx & (BATCH - 1);
  uint32_t kt0, kt1;
  tf2x32(0u, 1234u, 0u, (uint32_t)t, kt0, kt1);
  uint32_t r0 = rbits32(kt0, kt1, (uint32_t)(2 * b));
  uint32_t r1 = rbits32(kt0, kt1, (uint32_t)(2 * b + 1));
  g[idx] = make_float2(gumb_from_bits(r0), gumb_from_bits(r1));
}

// --------- Wh -> 3-term truncated-bf16 split, transposed [col][j] ---------
// w = w0 + w1 + w2 with |residual| <= 2^-24 |w| (truncation is exact in fp32)
__global__ void split_wht(const float* __restrict__ Wh, ushort* __restrict__ w0,
                          ushort* __restrict__ w1, ushort* __restrict__ w2) {
  int idx = blockIdx.x * 256 + threadIdx.x;   // 0..12287 = col*64 + j
  if (idx >= 192 * 64) return;
  int col = idx >> 6;
  int j   = idx & 63;
  float w = Wh[j * 192 + col];
  uint32_t u0 = __float_as_uint(w) & 0xffff0000u;
  float f0 = __uint_as_float(u0);
  float r1 = w - f0;
  uint32_t u1 = __float_as_uint(r1) & 0xffff0000u;
  float f1 = __uint_as_float(u1);
  float r2 = r1 - f1;
  uint32_t u2 = __float_as_uint(r2) & 0xffff0000u;
  w0[idx] = (ushort)(u0 >> 16);
  w1[idx] = (ushort)(u1 >> 16);
  w2[idx] = (ushort)(u2 >> 16);
}

// XLA's logistic_expander form: 0.5 + 0.5*tanh(0.5*x)
__device__ __forceinline__ float sigmoid_xla(float x) {
  return 0.5f + 0.5f * tanhf(0.5f * x);
}

#define MF(A_, B_, C_) __builtin_amdgcn_mfma_f32_16x16x32_bf16((A_), (B_), (C_), 0, 0, 0)
#define F4(v_, r_) (((const float*)&(v_))[r_])

// ================= MFMA kernel: 16 samples per wave =======================
// mh^T = WhT @ h  as [192,64]@[64,16].  D layout (HW, m89): col(lane&15)=sample,
// row(4*(lane>>4)+reg)=unit-within-tile.  A-frag: lane holds WhT[16*mt+(l&15)]
// [k=32*kc+8*hi+i]; B-frag: h[k][sample=l&15] with the SAME k-map (self-
// consistent pairing => correct for any HW k-order).  All three bf16 splits
// of WhT stay in registers (AGPR parking is free for MFMA operands).
__global__ __launch_bounds__(64) __attribute__((amdgpu_waves_per_eu(1, 1)))
void rnn_mfma(const float* __restrict__ Wi, const float* __restrict__ bb,
              const float* __restrict__ Wd, const float* __restrict__ bd,
              const ushort* __restrict__ w0p, const ushort* __restrict__ w1p,
              const ushort* __restrict__ w2p, const float2* __restrict__ g,
              float* __restrict__ out_s, float* __restrict__ out_lp) {
  __shared__ __align__(16) float h_lds[16 * 68];   // [sample][unit], pad 68
  __shared__ __align__(16) float c0zr[128];        // b0+b1 for z,r cols
  __shared__ __align__(16) float bh0a[64], bh1a[64];  // b0_h, b1_h
  __shared__ __align__(16) float cw0[192], cw1[192];  // Wi rows 0/1
  __shared__ __align__(16) float wd0a[64], wd1a[64];

  const int l = threadIdx.x, s = l & 15, hi = l >> 4;
  const int base = blockIdx.x * 16;

  for (int u = l; u < 128; u += 64) c0zr[u] = bb[u] + bb[192 + u];
  bh0a[l] = bb[128 + l];
  bh1a[l] = bb[320 + l];
  wd0a[l] = Wd[2 * l];
  wd1a[l] = Wd[2 * l + 1];
  for (int u = l; u < 192; u += 64) { cw0[u] = Wi[u]; cw1[u] = Wi[192 + u]; }
  for (int k = l; k < 16 * 68; k += 64) h_lds[k] = 0.0f;
  __syncthreads();

  // ---- A fragments: 3 splits x 12 m-tiles x 2 k-chunks ----
  v8s A0[12][2], A1[12][2], A2[12][2];
#pragma unroll
  for (int mt = 0; mt < 12; ++mt)
#pragma unroll
    for (int kc = 0; kc < 2; ++kc) {
      const int off = (16 * mt + s) * 64 + 32 * kc + 8 * hi;
      A0[mt][kc] = *reinterpret_cast<const v8s*>(w0p + off);
      A1[mt][kc] = *reinterpret_cast<const v8s*>(w1p + off);
      A2[mt][kc] = *reinterpret_cast<const v8s*>(w2p + off);
    }

  const float bd0 = bd[0], bd1 = bd[1];
  float hreg[4][4];
#pragma unroll
  for (int a = 0; a < 4; ++a)
#pragma unroll
    for (int r = 0; r < 4; ++r) hreg[a][r] = 0.0f;

  float lp = 0.0f;
  int spv = 0;
  float fsel = 0.0f;   // 0 at t=0 (zero input), 1 afterwards

  for (int t = 0; t < NSITES; ++t) {
    // ---- B fragments: previous h, 3-term truncated-bf16 split ----
    v8s B0[2], B1[2], B2[2];
#pragma unroll
    for (int kc = 0; kc < 2; ++kc) {
      const float4 ha = *reinterpret_cast<const float4*>(&h_lds[s * 68 + 32 * kc + 8 * hi]);
      const float4 hb = *reinterpret_cast<const float4*>(&h_lds[s * 68 + 32 * kc + 8 * hi + 4]);
      const float hv[8] = {ha.x, ha.y, ha.z, ha.w, hb.x, hb.y, hb.z, hb.w};
#pragma unroll
      for (int i = 0; i < 8; ++i) {
        const uint32_t u0 = __float_as_uint(hv[i]) & 0xffff0000u;
        const float f0 = __uint_as_float(u0);
        const float r1 = hv[i] - f0;
        const uint32_t u1 = __float_as_uint(r1) & 0xffff0000u;
        const float f1 = __uint_as_float(u1);
        const float r2 = r1 - f1;
        const uint32_t u2 = __float_as_uint(r2) & 0xffff0000u;
        B0[kc][i] = (short)(u0 >> 16);
        B1[kc][i] = (short)(u1 >> 16);
        B2[kc][i] = (short)(u2 >> 16);
      }
    }

    // ---- 12 tiles x 9 split-products x 2 kc, accumulated low -> high ----
    v4f acc[12];
#pragma unroll
    for (int mt = 0; mt < 12; ++mt) {
      v4f a = {0.0f, 0.0f, 0.0f, 0.0f};
#pragma unroll
      for (int kc = 0; kc < 2; ++kc) a = MF(A2[mt][kc], B2[kc], a);
#pragma unroll
      for (int kc = 0; kc < 2; ++kc) a = MF(A2[mt][kc], B1[kc], a);
#pragma unroll
      for (int kc = 0; kc < 2; ++kc) a = MF(A1[mt][kc], B2[kc], a);
#pragma unroll
      for (int kc = 0; kc < 2; ++kc) a = MF(A2[mt][kc], B0[kc], a);
#pragma unroll
      for (int kc = 0; kc < 2; ++kc) a = MF(A0[mt][kc], B2[kc], a);
#pragma unroll
      for (int kc = 0; kc < 2; ++kc) a = MF(A1[mt][kc], B1[kc], a);
#pragma unroll
      for (int kc = 0; kc < 2; ++kc) a = MF(A1[mt][kc], B0[kc], a);
#pragma unroll
      for (int kc = 0; kc < 2; ++kc) a = MF(A0[mt][kc], B1[kc], a);
#pragma unroll
      for (int kc = 0; kc < 2; ++kc) a = MF(A0[mt][kc], B0[kc], a);
      acc[mt] = a;
    }

    // ---- gates + h update + logits partials (lane = sample s, 16 units) --
    float pl0 = 0.0f, pl1 = 0.0f;
#pragma unroll
    for (int mt = 0; mt < 4; ++mt) {
      const int u0i = 16 * mt + 4 * hi;
      const float4 czv  = *reinterpret_cast<const float4*>(&c0zr[u0i]);
      const float4 crv  = *reinterpret_cast<const float4*>(&c0zr[64 + u0i]);
      const float4 bh0v = *reinterpret_cast<const float4*>(&bh0a[u0i]);
      const float4 bh1v = *reinterpret_cast<const float4*>(&bh1a[u0i]);
      const float4 wz0  = *reinterpret_cast<const float4*>(&cw0[u0i]);
      const float4 wz1  = *reinterpret_cast<const float4*>(&cw1[u0i]);
      const float4 wr0  = *reinterpret_cast<const float4*>(&cw0[64 + u0i]);
      const float4 wr1  = *reinterpret_cast<const float4*>(&cw1[64 + u0i]);
      const float4 wh0  = *reinterpret_cast<const float4*>(&cw0[128 + u0i]);
      const float4 wh1  = *reinterpret_cast<const float4*>(&cw1[128 + u0i]);
      const float4 wdl0 = *reinterpret_cast<const float4*>(&wd0a[u0i]);
      const float4 wdl1 = *reinterpret_cast<const float4*>(&wd1a[u0i]);
      float4 hstore;
#pragma unroll
      for (int r = 0; r < 4; ++r) {
        const float selz = fsel * (spv ? F4(wz1, r) : F4(wz0, r));
        const float selr = fsel * (spv ? F4(wr1, r) : F4(wr0, r));
        const float selh = fsel * (spv ? F4(wh1, r) : F4(wh0, r));
        const float zin = acc[mt][r] + F4(czv, r) + selz;
        const float rin = acc[mt + 4][r] + F4(crv, r) + selr;
        const float rhv = acc[mt + 8][r] + F4(bh1v, r);
        const float xhv = F4(bh0v, r) + selh;
        const float zg = sigmoid_xla(zin);
        const float rg = sigmoid_xla(rin);
        const float hg = tanhf(xhv + rg * rhv);
        const float hold = hreg[mt][r];
        const float hn = zg * hold + (1.0f - zg) * hg;
        hreg[mt][r] = hn;
        ((float*)&hstore)[r] = hn;
        pl0 = fmaf(hn, F4(wdl0, r), pl0);
        pl1 = fmaf(hn, F4(wdl1, r), pl1);
      }
      *reinterpret_cast<float4*>(&h_lds[s * 68 + u0i]) = hstore;
    }

    // quad reduce (lanes s, s+16, s+32, s+48 share the sample)
    pl0 += __shfl_xor(pl0, 16, 64);
    pl0 += __shfl_xor(pl0, 32, 64);
    pl1 += __shfl_xor(pl1, 16, 64);
    pl1 += __shfl_xor(pl1, 32, 64);
    const float l0 = pl0 + bd0, l1 = pl1 + bd1;

    const float2 gc = g[t * BATCH + base + s];
    const float mmax = fmaxf(l0, l1);
    const float sh0 = l0 - mmax, sh1 = l1 - mmax;
    const float lse = logf(expf(sh0) + expf(sh1));
    const int sc = ((l1 + gc.y) > (l0 + gc.x)) ? 1 : 0;
    lp += (sc ? sh1 : sh0) - lse;
    if (hi == 0) out_s[(size_t)(base + s) * NSITES + t] = (float)sc;
    spv = sc;
    fsel = 1.0f;
    __syncthreads();   // order h_lds writes before next iteration's reads
  }

  if (hi == 0) out_lp[base + s] = 0.5f * lp;
}

// ---------------- fallback (ws too small): proven bit-exact path ----------
__global__ __launch_bounds__(64)
void rnn_plain(const float* __restrict__ Wi, const float* __restrict__ Wh,
               const float* __restrict__ bb, const float* __restrict__ Wd,
               const float* __restrict__ bd,
               float* __restrict__ out_s, float* __restrict__ out_lp) {
  const int lane = threadIdx.x;
  const int b = blockIdx.x;

  float wz[NHID], wr[NHID], wh[NHID];
#pragma unroll
  for (int j = 0; j < NHID; ++j) {
    wz[j] = Wh[j * 192 + lane];
    wr[j] = Wh[j * 192 + 64 + lane];
    wh[j] = Wh[j * 192 + 128 + lane];
  }
  const float b1z = bb[192 + lane];
  const float b1r = bb[192 + 64 + lane];
  const float b1h = bb[192 + 128 + lane];
  const float m0z = bb[lane], m0r = bb[64 + lane], m0h = bb[128 + lane];
  const float m1z = Wi[lane] + m0z, m1r = Wi[64 + lane] + m0r, m1h = Wi[128 + lane] + m0h;
  const float m2z = Wi[192 + lane] + m0z, m2r = Wi[192 + 64 + lane] + m0r,
              m2h = Wi[192 + 128 + lane] + m0h;
  const float wd0 = Wd[lane * 2 + 0], wd1 = Wd[lane * 2 + 1];
  const float bd0 = bd[0], bd1 = bd[1];

  float h = 0.0f, lpsum = 0.0f;
  float xz = m0z, xr = m0r, xh = m0h;

  for (int t = 0; t < NSITES; ++t) {
    uint32_t kt0, kt1;
    tf2x32(0u, 1234u, 0u, (uint32_t)t, kt0, kt1);
    const float g0 = gumb_from_bits(rbits32(kt0, kt1, (uint32_t)(2 * b)));
    const float g1 = gumb_from_bits(rbits32(kt0, kt1, (uint32_t)(2 * b + 1)));

    float az = 0.0f, ar = 0.0f, ah = 0.0f;
#pragma unroll
    for (int j = 0; j < NHID; ++j) {
      const float hj = __int_as_float(__builtin_amdgcn_readlane(__float_as_int(h), j));
      az = fmaf(hj, wz[j], az);
      ar = fmaf(hj, wr[j], ar);
      ah = fmaf(hj, wh[j], ah);
    }
    const float rz = az + b1z, rr = ar + b1r, rh = ah + b1h;
    const float zg = sigmoid_xla(xz + rz);
    const float rg = sigmoid_xla(xr + rr);
    const float hg = tanhf(xh + rg * rh);
    h = zg * h + (1.0f - zg) * hg;

    float p0 = h * wd0, p1 = h * wd1;
#pragma unroll
    for (int off = 32; off > 0; off >>= 1) {
      p0 += __shfl_xor(p0, off, 64);
      p1 += __shfl_xor(p1, off, 64);
    }
    const float l0 = p0 + bd0, l1 = p1 + bd1;
    const float mmax = fmaxf(l0, l1);
    const float sh0 = l0 - mmax, sh1 = l1 - mmax;
    const float lse = logf(expf(sh0) + expf(sh1));
    const int s = ((l1 + g1) > (l0 + g0)) ? 1 : 0;
    lpsum += (s ? sh1 : sh0) - lse;
    if (lane == 0) out_s[(size_t)b * NSITES + t] = (float)s;
    xz = s ? m2z : m1z;
    xr = s ? m2r : m1r;
    xh = s ? m2h : m1h;
  }

  if (lane == 0) out_lp[b] = 0.5f * lpsum;
}

extern "C" void kernel_launch(void* const* d_in, const int* in_sizes, int n_in,
                              void* d_out, int out_size, void* d_ws, size_t ws_size,
                              hipStream_t stream) {
  const float* Wi = (const float*)d_in[1];
  const float* Wh = (const float*)d_in[2];
  const float* bb = (const float*)d_in[3];
  const float* Wd = (const float*)d_in[4];
  const float* bd = (const float*)d_in[5];

  float* out    = (float*)d_out;
  float* out_s  = out;                           // [8192][256]
  float* out_lp = out + (size_t)BATCH * NSITES;  // [8192]

  const size_t gbytes = (size_t)NSITES * BATCH * sizeof(float2);  // 16 MiB
  const size_t wb = (size_t)192 * 64 * sizeof(ushort);            // 24 KiB

  if (ws_size >= gbytes + 3 * wb) {
    float2* g  = (float2*)d_ws;
    ushort* w0 = (ushort*)((char*)d_ws + gbytes);
    ushort* w1 = w0 + 192 * 64;
    ushort* w2 = w1 + 192 * 64;
    gumbel_precompute<<<(NSITES * BATCH) / 256, 256, 0, stream>>>(g);
    split_wht<<<48, 256, 0, stream>>>(Wh, w0, w1, w2);
    rnn_mfma<<<BATCH / 16, 64, 0, stream>>>(Wi, bb, Wd, bd, w0, w1, w2, g, out_s, out_lp);
  } else {
    rnn_plain<<<BATCH, 64, 0, stream>>>(Wi, Wh, bb, Wd, bd, out_s, out_lp);
  }
}

// Round 10
// 565.991 us; speedup vs baseline: 3.9832x; 2.3506x over previous
//
#include <hip/hip_runtime.h>
#include <stdint.h>

#define NSITES 256
#define NHID   64
#define BATCH  8192

typedef float v4f __attribute__((ext_vector_type(4)));
typedef short v8s __attribute__((ext_vector_type(8)));

// ---------------- threefry2x32 (exact JAX semantics) ----------------
__device__ __forceinline__ uint32_t rotl32(uint32_t v, int d) {
  return (v << d) | (v >> (32 - d));
}

__device__ __forceinline__ void tf2x32(uint32_t k0, uint32_t k1,
                                       uint32_t x0, uint32_t x1,
                                       uint32_t& o0, uint32_t& o1) {
  uint32_t ks2 = k0 ^ k1 ^ 0x1BD11BDAu;
  x0 += k0; x1 += k1;
#define TFR4(a,b,c,d) \
  x0 += x1; x1 = rotl32(x1,a); x1 ^= x0; \
  x0 += x1; x1 = rotl32(x1,b); x1 ^= x0; \
  x0 += x1; x1 = rotl32(x1,c); x1 ^= x0; \
  x0 += x1; x1 = rotl32(x1,d); x1 ^= x0;
  TFR4(13,15,26,6)   x0 += k1;  x1 += ks2 + 1u;
  TFR4(17,29,16,24)  x0 += ks2; x1 += k0  + 2u;
  TFR4(13,15,26,6)   x0 += k0;  x1 += k1  + 3u;
  TFR4(17,29,16,24)  x0 += k1;  x1 += ks2 + 4u;
  TFR4(13,15,26,6)   x0 += ks2; x1 += k0  + 5u;
#undef TFR4
  o0 = x0; o1 = x1;
}

__device__ __forceinline__ float gumb_from_bits(uint32_t bits) {
  float f = __uint_as_float((bits >> 9) | 0x3f800000u) - 1.0f;
  float u = (f == 0.0f) ? 1.17549435e-38f : f;
  return -logf(-logf(u));
}

__device__ __forceinline__ uint32_t rbits32(uint32_t k0, uint32_t k1, uint32_t e) {
  uint32_t a, b;
  tf2x32(k0, k1, 0u, e, a, b);
  return a ^ b;
}

__global__ void gumbel_precompute(float2* __restrict__ g) {
  int idx = blockIdx.x * blockDim.x + threadIdx.x;
  if (idx >= NSITES * BATCH) return;
  int t = idx >> 13;
  int b = idx & (BATCH - 1);
  uint32_t kt0, kt1;
  tf2x32(0u, 1234u, 0u, (uint32_t)t, kt0, kt1);
  uint32_t r0 = rbits32(kt0, kt1, (uint32_t)(2 * b));
  uint32_t r1 = rbits32(kt0, kt1, (uint32_t)(2 * b + 1));
  g[idx] = make_float2(gumb_from_bits(r0), gumb_from_bits(r1));
}

// --------- Wh -> 3-term truncated-bf16 split, transposed [col][j] ---------
// exact: w = w0 + w1 + w2 (3x8 mantissa bits = fp32's 24)
__global__ void split_wht(const float* __restrict__ Wh, ushort* __restrict__ w0,
                          ushort* __restrict__ w1, ushort* __restrict__ w2) {
  int idx = blockIdx.x * 256 + threadIdx.x;   // 0..12287 = col*64 + j
  if (idx >= 192 * 64) return;
  int col = idx >> 6;
  int j   = idx & 63;
  float w = Wh[j * 192 + col];
  uint32_t u0 = __float_as_uint(w) & 0xffff0000u;
  float f0 = __uint_as_float(u0);
  float r1 = w - f0;
  uint32_t u1 = __float_as_uint(r1) & 0xffff0000u;
  float f1 = __uint_as_float(u1);
  float r2 = r1 - f1;
  uint32_t u2 = __float_as_uint(r2) & 0xffff0000u;
  w0[idx] = (ushort)(u0 >> 16);
  w1[idx] = (ushort)(u1 >> 16);
  w2[idx] = (ushort)(u2 >> 16);
}

// XLA's logistic_expander form: 0.5 + 0.5*tanh(0.5*x)
__device__ __forceinline__ float sigmoid_xla(float x) {
  return 0.5f + 0.5f * tanhf(0.5f * x);
}

#define MF(A_, B_, C_) __builtin_amdgcn_mfma_f32_16x16x32_bf16((A_), (B_), (C_), 0, 0, 0)
#define F4(v_, r_) (((const float*)&(v_))[r_])

// ============ MFMA kernel: 16 samples per block, 4 waves ==================
// Wave w owns tile-triple {w, 4+w, 8+w} = units 16w..16w+15 for z,r,h.
// h recirculates through double-buffered LDS (one barrier per step).
// Logits/decisions are recomputed redundantly by every wave with the exact
// same fmaf chain + shfl tree as R9 -> bit-identical everywhere.
__global__ __launch_bounds__(256)
void rnn_mfma4(const float* __restrict__ Wi, const float* __restrict__ bb,
               const float* __restrict__ Wd, const float* __restrict__ bd,
               const ushort* __restrict__ w0p, const ushort* __restrict__ w1p,
               const ushort* __restrict__ w2p, const float2* __restrict__ g,
               float* __restrict__ out_s, float* __restrict__ out_lp) {
  __shared__ __align__(16) float hb[2][16 * 68];      // double-buffered h
  __shared__ __align__(16) float c0zr[128];           // b0+b1 for z,r
  __shared__ __align__(16) float bh0a[64], bh1a[64];  // b0_h, b1_h
  __shared__ __align__(16) float cw0[192], cw1[192];  // Wi rows 0/1
  __shared__ __align__(16) float wd0a[64], wd1a[64];

  const int tid = threadIdx.x;
  const int l = tid & 63, s = l & 15, hi = l >> 4;
  const int w = tid >> 6;                 // wave id 0..3
  const int base = blockIdx.x * 16;

  if (tid < 64) {
    c0zr[tid] = bb[tid] + bb[192 + tid];
    c0zr[tid + 64] = bb[tid + 64] + bb[256 + tid];
    bh0a[tid] = bb[128 + tid];
    bh1a[tid] = bb[320 + tid];
    wd0a[tid] = Wd[2 * tid];
    wd1a[tid] = Wd[2 * tid + 1];
    cw0[tid] = Wi[tid]; cw0[tid + 64] = Wi[tid + 64]; cw0[tid + 128] = Wi[tid + 128];
    cw1[tid] = Wi[192 + tid]; cw1[tid + 64] = Wi[256 + tid]; cw1[tid + 128] = Wi[320 + tid];
  }
  for (int k = tid; k < 16 * 68; k += 256) hb[0][k] = 0.0f;
  __syncthreads();

  // ---- A fragments: 3 splits x 3 tiles {w,4+w,8+w} x 2 k-chunks ----
  v8s A0[3][2], A1[3][2], A2[3][2];
#pragma unroll
  for (int i3 = 0; i3 < 3; ++i3) {
    const int tile = w + 4 * i3;
#pragma unroll
    for (int kc = 0; kc < 2; ++kc) {
      const int off = (16 * tile + s) * 64 + 32 * kc + 8 * hi;
      A0[i3][kc] = *reinterpret_cast<const v8s*>(w0p + off);
      A1[i3][kc] = *reinterpret_cast<const v8s*>(w1p + off);
      A2[i3][kc] = *reinterpret_cast<const v8s*>(w2p + off);
    }
  }

  const float bd0 = bd[0], bd1 = bd[1];
  const int u0i = 16 * w + 4 * hi;        // this wave's gate-unit group
  const float4 czv  = *reinterpret_cast<const float4*>(&c0zr[u0i]);
  const float4 crv  = *reinterpret_cast<const float4*>(&c0zr[64 + u0i]);
  const float4 bh0v = *reinterpret_cast<const float4*>(&bh0a[u0i]);
  const float4 bh1v = *reinterpret_cast<const float4*>(&bh1a[u0i]);
  const float4 wz0  = *reinterpret_cast<const float4*>(&cw0[u0i]);
  const float4 wz1  = *reinterpret_cast<const float4*>(&cw1[u0i]);
  const float4 wr0  = *reinterpret_cast<const float4*>(&cw0[64 + u0i]);
  const float4 wr1  = *reinterpret_cast<const float4*>(&cw1[64 + u0i]);
  const float4 wh0  = *reinterpret_cast<const float4*>(&cw0[128 + u0i]);
  const float4 wh1  = *reinterpret_cast<const float4*>(&cw1[128 + u0i]);

  float hreg[4] = {0.0f, 0.0f, 0.0f, 0.0f};
  float lp = 0.0f;
  int spv = 0, p = 0;
  float fsel = 0.0f;   // 0 at t=0 (zero input), 1 afterwards

  for (int t = 0; t < NSITES; ++t) {
    // gumbel for this step (issued early; used ~1000 cyc later)
    const float2 gc = g[t * BATCH + base + s];

    // ---- B fragments from hb[p]: 3-term truncated-bf16 split ----
    v8s B0[2], B1[2], B2[2];
#pragma unroll
    for (int kc = 0; kc < 2; ++kc) {
      const float4 ha = *reinterpret_cast<const float4*>(&hb[p][s * 68 + 32 * kc + 8 * hi]);
      const float4 hcb = *reinterpret_cast<const float4*>(&hb[p][s * 68 + 32 * kc + 8 * hi + 4]);
      const float hv[8] = {ha.x, ha.y, ha.z, ha.w, hcb.x, hcb.y, hcb.z, hcb.w};
#pragma unroll
      for (int i = 0; i < 8; ++i) {
        const uint32_t u0 = __float_as_uint(hv[i]) & 0xffff0000u;
        const float f0 = __uint_as_float(u0);
        const float r1 = hv[i] - f0;
        const uint32_t u1 = __float_as_uint(r1) & 0xffff0000u;
        const float f1 = __uint_as_float(u1);
        const float r2 = r1 - f1;
        const uint32_t u2 = __float_as_uint(r2) & 0xffff0000u;
        B0[kc][i] = (short)(u0 >> 16);
        B1[kc][i] = (short)(u1 >> 16);
        B2[kc][i] = (short)(u2 >> 16);
      }
    }

    // ---- 3 tiles x 9 split-products x 2 kc, low -> high (same order) ----
    v4f acc[3];
#pragma unroll
    for (int i3 = 0; i3 < 3; ++i3) {
      v4f a = {0.0f, 0.0f, 0.0f, 0.0f};
#pragma unroll
      for (int kc = 0; kc < 2; ++kc) a = MF(A2[i3][kc], B2[kc], a);
#pragma unroll
      for (int kc = 0; kc < 2; ++kc) a = MF(A2[i3][kc], B1[kc], a);
#pragma unroll
      for (int kc = 0; kc < 2; ++kc) a = MF(A1[i3][kc], B2[kc], a);
#pragma unroll
      for (int kc = 0; kc < 2; ++kc) a = MF(A2[i3][kc], B0[kc], a);
#pragma unroll
      for (int kc = 0; kc < 2; ++kc) a = MF(A0[i3][kc], B2[kc], a);
#pragma unroll
      for (int kc = 0; kc < 2; ++kc) a = MF(A1[i3][kc], B1[kc], a);
#pragma unroll
      for (int kc = 0; kc < 2; ++kc) a = MF(A1[i3][kc], B0[kc], a);
#pragma unroll
      for (int kc = 0; kc < 2; ++kc) a = MF(A0[i3][kc], B1[kc], a);
#pragma unroll
      for (int kc = 0; kc < 2; ++kc) a = MF(A0[i3][kc], B0[kc], a);
      acc[i3] = a;
    }

    // ---- gates + h update for this wave's 16 units (identical math) ----
    float4 hstore;
#pragma unroll
    for (int r = 0; r < 4; ++r) {
      const float selz = fsel * (spv ? F4(wz1, r) : F4(wz0, r));
      const float selr = fsel * (spv ? F4(wr1, r) : F4(wr0, r));
      const float selh = fsel * (spv ? F4(wh1, r) : F4(wh0, r));
      const float zin = acc[0][r] + F4(czv, r) + selz;
      const float rin = acc[1][r] + F4(crv, r) + selr;
      const float rhv = acc[2][r] + F4(bh1v, r);
      const float xhv = F4(bh0v, r) + selh;
      const float zg = sigmoid_xla(zin);
      const float rg = sigmoid_xla(rin);
      const float hg = tanhf(xhv + rg * rhv);
      const float hn = zg * hreg[r] + (1.0f - zg) * hg;
      hreg[r] = hn;
      ((float*)&hstore)[r] = hn;
    }
    *reinterpret_cast<float4*>(&hb[p ^ 1][s * 68 + u0i]) = hstore;

    __syncthreads();   // h(t) complete & visible

    // ---- logits: every wave, exact R9 chain (mt ascending, r ascending) --
    float pl0 = 0.0f, pl1 = 0.0f;
#pragma unroll
    for (int mt = 0; mt < 4; ++mt) {
      const int ui = 16 * mt + 4 * hi;
      const float4 hv4  = *reinterpret_cast<const float4*>(&hb[p ^ 1][s * 68 + ui]);
      const float4 wdl0 = *reinterpret_cast<const float4*>(&wd0a[ui]);
      const float4 wdl1 = *reinterpret_cast<const float4*>(&wd1a[ui]);
#pragma unroll
      for (int r = 0; r < 4; ++r) {
        pl0 = fmaf(F4(hv4, r), F4(wdl0, r), pl0);
        pl1 = fmaf(F4(hv4, r), F4(wdl1, r), pl1);
      }
    }
    pl0 += __shfl_xor(pl0, 16, 64);
    pl0 += __shfl_xor(pl0, 32, 64);
    pl1 += __shfl_xor(pl1, 16, 64);
    pl1 += __shfl_xor(pl1, 32, 64);
    const float l0 = pl0 + bd0, l1 = pl1 + bd1;

    const float mmax = fmaxf(l0, l1);
    const float sh0 = l0 - mmax, sh1 = l1 - mmax;
    const float lse = logf(expf(sh0) + expf(sh1));
    const int sc = ((l1 + gc.y) > (l0 + gc.x)) ? 1 : 0;
    lp += (sc ? sh1 : sh0) - lse;
    if (tid < 16) out_s[(size_t)(base + s) * NSITES + t] = (float)sc;
    spv = sc;
    fsel = 1.0f;
    p ^= 1;
  }

  if (tid < 16) out_lp[base + s] = 0.5f * lp;
}

// ---------------- fallback (ws too small): proven bit-exact path ----------
__global__ __launch_bounds__(64)
void rnn_plain(const float* __restrict__ Wi, const float* __restrict__ Wh,
               const float* __restrict__ bb, const float* __restrict__ Wd,
               const float* __restrict__ bd,
               float* __restrict__ out_s, float* __restrict__ out_lp) {
  const int lane = threadIdx.x;
  const int b = blockIdx.x;

  float wz[NHID], wr[NHID], wh[NHID];
#pragma unroll
  for (int j = 0; j < NHID; ++j) {
    wz[j] = Wh[j * 192 + lane];
    wr[j] = Wh[j * 192 + 64 + lane];
    wh[j] = Wh[j * 192 + 128 + lane];
  }
  const float b1z = bb[192 + lane];
  const float b1r = bb[192 + 64 + lane];
  const float b1h = bb[192 + 128 + lane];
  const float m0z = bb[lane], m0r = bb[64 + lane], m0h = bb[128 + lane];
  const float m1z = Wi[lane] + m0z, m1r = Wi[64 + lane] + m0r, m1h = Wi[128 + lane] + m0h;
  const float m2z = Wi[192 + lane] + m0z, m2r = Wi[192 + 64 + lane] + m0r,
              m2h = Wi[192 + 128 + lane] + m0h;
  const float wd0 = Wd[lane * 2 + 0], wd1 = Wd[lane * 2 + 1];
  const float bd0 = bd[0], bd1 = bd[1];

  float h = 0.0f, lpsum = 0.0f;
  float xz = m0z, xr = m0r, xh = m0h;

  for (int t = 0; t < NSITES; ++t) {
    uint32_t kt0, kt1;
    tf2x32(0u, 1234u, 0u, (uint32_t)t, kt0, kt1);
    const float g0 = gumb_from_bits(rbits32(kt0, kt1, (uint32_t)(2 * b)));
    const float g1 = gumb_from_bits(rbits32(kt0, kt1, (uint32_t)(2 * b + 1)));

    float az = 0.0f, ar = 0.0f, ah = 0.0f;
#pragma unroll
    for (int j = 0; j < NHID; ++j) {
      const float hj = __int_as_float(__builtin_amdgcn_readlane(__float_as_int(h), j));
      az = fmaf(hj, wz[j], az);
      ar = fmaf(hj, wr[j], ar);
      ah = fmaf(hj, wh[j], ah);
    }
    const float rz = az + b1z, rr = ar + b1r, rh = ah + b1h;
    const float zg = sigmoid_xla(xz + rz);
    const float rg = sigmoid_xla(xr + rr);
    const float hg = tanhf(xh + rg * rh);
    h = zg * h + (1.0f - zg) * hg;

    float p0 = h * wd0, p1 = h * wd1;
#pragma unroll
    for (int off = 32; off > 0; off >>= 1) {
      p0 += __shfl_xor(p0, off, 64);
      p1 += __shfl_xor(p1, off, 64);
    }
    const float l0 = p0 + bd0, l1 = p1 + bd1;
    const float mmax = fmaxf(l0, l1);
    const float sh0 = l0 - mmax, sh1 = l1 - mmax;
    const float lse = logf(expf(sh0) + expf(sh1));
    const int s = ((l1 + g1) > (l0 + g0)) ? 1 : 0;
    lpsum += (s ? sh1 : sh0) - lse;
    if (lane == 0) out_s[(size_t)b * NSITES + t] = (float)s;
    xz = s ? m2z : m1z;
    xr = s ? m2r : m1r;
    xh = s ? m2h : m1h;
  }

  if (lane == 0) out_lp[b] = 0.5f * lpsum;
}

extern "C" void kernel_launch(void* const* d_in, const int* in_sizes, int n_in,
                              void* d_out, int out_size, void* d_ws, size_t ws_size,
                              hipStream_t stream) {
  const float* Wi = (const float*)d_in[1];
  const float* Wh = (const float*)d_in[2];
  const float* bb = (const float*)d_in[3];
  const float* Wd = (const float*)d_in[4];
  const float* bd = (const float*)d_in[5];

  float* out    = (float*)d_out;
  float* out_s  = out;                           // [8192][256]
  float* out_lp = out + (size_t)BATCH * NSITES;  // [8192]

  const size_t gbytes = (size_t)NSITES * BATCH * sizeof(float2);  // 16 MiB
  const size_t wb = (size_t)192 * 64 * sizeof(ushort);            // 24 KiB

  if (ws_size >= gbytes + 3 * wb) {
    float2* g  = (float2*)d_ws;
    ushort* w0 = (ushort*)((char*)d_ws + gbytes);
    ushort* w1 = w0 + 192 * 64;
    ushort* w2 = w1 + 192 * 64;
    gumbel_precompute<<<(NSITES * BATCH) / 256, 256, 0, stream>>>(g);
    split_wht<<<48, 256, 0, stream>>>(Wh, w0, w1, w2);
    rnn_mfma4<<<BATCH / 16, 256, 0, stream>>>(Wi, bb, Wd, bd, w0, w1, w2, g, out_s, out_lp);
  } else {
    rnn_plain<<<BATCH, 64, 0, stream>>>(Wi, Wh, bb, Wd, bd, out_s, out_lp);
  }
}